// Round 4
// baseline (161.255 us; speedup 1.0000x reference)
//
#include <hip/hip_runtime.h>
#include <hip/hip_bf16.h>

typedef __attribute__((ext_vector_type(8))) short short8;       // 8 x bf16 (4 VGPR)
typedef __attribute__((ext_vector_type(4))) float f32x4;        // MFMA acc / float4
typedef __attribute__((ext_vector_type(2))) float f32x2;
typedef __attribute__((ext_vector_type(4))) unsigned short ushort4v;
typedef __attribute__((ext_vector_type(2))) unsigned int uint32x2;

__device__ __forceinline__ unsigned short f2bf(float f) {
    __hip_bfloat16 h = __float2bfloat16(f);
    return __builtin_bit_cast(unsigned short, h);
}
__device__ __forceinline__ unsigned int pack2(float a, float b) {
    return (unsigned int)f2bf(a) | ((unsigned int)f2bf(b) << 16);
}
__device__ __forceinline__ void gload_lds16(const void* g, void* l) {
    __builtin_amdgcn_global_load_lds((const __attribute__((address_space(1))) unsigned int*)g,
                                     (__attribute__((address_space(3))) unsigned int*)l, 16, 0, 0);
}

// ---------------- K0: w_qk fp32 -> bf16 ----------------
__global__ __launch_bounds__(256) void k0_cvt(const float* __restrict__ src,
                                              unsigned short* __restrict__ dst, int n) {
    int i = blockIdx.x * 256 + threadIdx.x;
    if (i < n) dst[i] = f2bf(src[i]);
}

// ---------------- K1: Q-GEMM + normalize, writes SWIZZLED qn ----------------
// (unchanged from round 3)
__global__ __launch_bounds__(256, 2) void k1_qgemm(const float* __restrict__ x,
                                                   const unsigned short* __restrict__ wbf,
                                                   unsigned short* __restrict__ qn) {
    const int blk = blockIdx.x;
    const int win = blk >> 3;
    const int t0  = (blk & 7) << 7;
    const int b   = win >> 2;
    const int h0  = ((win >> 1) & 1) << 5;
    const int w0  = (win & 1) << 5;

    __shared__ __align__(16) unsigned short lA[256][40];  // W tile [c][k]
    __shared__ __align__(16) unsigned short lB[128][40];  // X tile [t][k]
    __shared__ float nbuf[4][128];

    const int tid  = threadIdx.x;
    const int lane = tid & 63;
    const int wv   = tid >> 6;
    const int lo   = lane & 15;
    const int hi   = lane >> 4;

    f32x4 acc[4][8];
#pragma unroll
    for (int mi = 0; mi < 4; ++mi)
#pragma unroll
        for (int ni = 0; ni < 8; ++ni) acc[mi][ni] = (f32x4){0.f, 0.f, 0.f, 0.f};

    const float* xblk = x + (size_t)b * 512 * 4096 + (size_t)(h0 + (t0 >> 5)) * 64 + w0;

    const int tp = tid & 63;
    const int cg = tid >> 6;
    const int tt = tp * 2;
    const int pos = ((tt >> 5) << 6) + (tt & 31);

    for (int kt = 0; kt < 16; ++kt) {
        const int k0 = kt << 5;
#pragma unroll
        for (int r = 0; r < 4; ++r) {
            int cid = r * 256 + tid;
            int c   = cid >> 2;
            int n8  = cid & 3;
            *(short8*)&lA[c][n8 * 8] = *(const short8*)(wbf + c * 512 + k0 + n8 * 8);
        }
        {
            const float* xp = xblk + (size_t)(k0 + cg * 8) * 4096 + pos;
            short8 v0, v1;
#pragma unroll
            for (int i = 0; i < 8; ++i) {
                f32x2 d = *(const f32x2*)(xp + (size_t)i * 4096);
                v0[i] = (short)f2bf(d[0]);
                v1[i] = (short)f2bf(d[1]);
            }
            *(short8*)&lB[tt][cg * 8]     = v0;
            *(short8*)&lB[tt + 1][cg * 8] = v1;
        }
        __syncthreads();

        short8 af[4], bfr[8];
#pragma unroll
        for (int mi = 0; mi < 4; ++mi)
            af[mi] = *(const short8*)&lA[wv * 64 + mi * 16 + lo][hi * 8];
#pragma unroll
        for (int ni = 0; ni < 8; ++ni)
            bfr[ni] = *(const short8*)&lB[ni * 16 + lo][hi * 8];
#pragma unroll
        for (int mi = 0; mi < 4; ++mi)
#pragma unroll
            for (int ni = 0; ni < 8; ++ni)
                acc[mi][ni] = __builtin_amdgcn_mfma_f32_16x16x32_bf16(af[mi], bfr[ni], acc[mi][ni], 0, 0, 0);
        __syncthreads();
    }

    float part[8];
#pragma unroll
    for (int ni = 0; ni < 8; ++ni) {
        float s = 0.f;
#pragma unroll
        for (int mi = 0; mi < 4; ++mi)
#pragma unroll
            for (int r = 0; r < 4; ++r) s += acc[mi][ni][r] * acc[mi][ni][r];
        s += __shfl_xor(s, 16);
        s += __shfl_xor(s, 32);
        part[ni] = s;
    }
    if (hi == 0) {
#pragma unroll
        for (int ni = 0; ni < 8; ++ni) nbuf[wv][ni * 16 + lo] = part[ni];
    }
    __syncthreads();

    char* qwin_out = (char*)(qn + (size_t)win * 1024 * 256);
#pragma unroll
    for (int ni = 0; ni < 8; ++ni) {
        const int tl = ni * 16 + lo;
        float s = nbuf[0][tl] + nbuf[1][tl] + nbuf[2][tl] + nbuf[3][tl];
        float inv = 1.f / (sqrtf(s) + 1e-6f);
        const int rq = t0 + tl;
        const int swz = (rq & 7) << 4;
#pragma unroll
        for (int mi = 0; mi < 4; ++mi) {
            int c = wv * 64 + mi * 16 + hi * 4;
            ushort4v o = {f2bf(acc[mi][ni][0] * inv), f2bf(acc[mi][ni][1] * inv),
                          f2bf(acc[mi][ni][2] * inv), f2bf(acc[mi][ni][3] * inv)};
            size_t off = ((size_t)rq * 512 + (size_t)(c * 2)) ^ (size_t)swz;
            *(ushort4v*)(qwin_out + off) = o;
        }
    }
}

// ---------------- K2: double-buffered 32-key chunks, prefetch-before-compute ----------------
// grid: 512 = 128 windows * 4 query-blocks (256 q); bid&127 = window (XCD swizzle).
__global__ __launch_bounds__(256, 2) void k2_attn(const unsigned short* __restrict__ qn,
                                                  const float* __restrict__ v,
                                                  float* __restrict__ out) {
    const int g   = blockIdx.x;
    const int win = g & 127;
    const int qb  = g >> 7;
    const int b   = win >> 2;
    const int h0  = ((win >> 1) & 1) << 5;
    const int w0  = (win & 1) << 5;

    __shared__ __align__(16) unsigned short lK[2][32 * 256];  // 2 x 16 KB, swizzled image
    __shared__ __align__(16) unsigned short lP[256][36];      // 72 B rows, wave-private
    __shared__ __align__(16) unsigned short lV[2][16][36];    // V^T [ch][key], row15 = ones

    const int tid  = threadIdx.x;
    const int lane = tid & 63;
    const int wv   = tid >> 6;
    const int lo   = lane & 15;
    const int hi   = lane >> 4;

    const char* qwin = (const char*)(qn + (size_t)win * 1024 * 256);
    const int qw0 = qb * 256 + wv * 64;

    // hoisted Q fragments (swizzled reads)
    short8 qa[4][8];
#pragma unroll
    for (int mi = 0; mi < 4; ++mi) {
        const int rq = qw0 + mi * 16 + lo;
        const size_t swz = (size_t)((rq & 7) << 4);
#pragma unroll
        for (int kc = 0; kc < 8; ++kc)
            qa[mi][kc] = *(const short8*)(qwin + (((size_t)rq * 512 + kc * 64 + hi * 16) ^ swz));
    }

    f32x4 accout[4];
#pragma unroll
    for (int t = 0; t < 4; ++t) accout[t] = (f32x4){0.f, 0.f, 0.f, 0.f};

    const float* vbase = v + (size_t)b * 15 * 4096 + (size_t)h0 * 64 + w0;
    const int chn = tid & 15;   // V-stage: channel
    const int kp  = tid >> 4;   // V-stage: key-pair 0..15

    // ---- prologue: stage chunk 0 ----
    {
        const char* src = qwin;
        char* dst = (char*)lK[0];
#pragma unroll
        for (int r = 0; r < 4; ++r) {
            int idx = (r * 256 + tid) * 16;
            gload_lds16(src + idx, dst + idx);
        }
        unsigned int u = 0x3F803F80u;
        if (chn < 15) {
            f32x2 d = *(const f32x2*)(vbase + (size_t)chn * 4096 + kp * 2);
            u = pack2(d[0], d[1]);
        }
        *(unsigned int*)((char*)lV[0] + chn * 72 + kp * 4) = u;
    }
    __syncthreads();

    int buf = 0;
    for (int chk = 0; chk < 32; ++chk) {
        const bool pre = (chk < 31);
        f32x2 vpre;
        // ---- prefetch next chunk (issue early; latency hides under compute) ----
        if (pre) {
            const char* src = qwin + (size_t)(chk + 1) * 32 * 512;
            char* dst = (char*)lK[buf ^ 1];
#pragma unroll
            for (int r = 0; r < 4; ++r) {
                int idx = (r * 256 + tid) * 16;
                gload_lds16(src + idx, dst + idx);
            }
            if (chn < 15)
                vpre = *(const f32x2*)(vbase + (size_t)chn * 4096 + ((chk + 1) * 64 + kp * 2));
        }

        // ---- S^T on lK[buf]: D = mfma(A=kb, B=qa) ----
        const char* lKb = (const char*)lK[buf];
#pragma unroll
        for (int ni = 0; ni < 2; ++ni) {
            f32x4 st[4];
#pragma unroll
            for (int mi = 0; mi < 4; ++mi) st[mi] = (f32x4){0.f, 0.f, 0.f, 0.f};
#pragma unroll
            for (int kc = 0; kc < 8; ++kc) {
                const int row = ni * 16 + lo;
                const int off = (row * 512 + kc * 64 + hi * 16) ^ ((row & 7) << 4);
                short8 kb = *(const short8*)(lKb + off);
#pragma unroll
                for (int mi = 0; mi < 4; ++mi)
                    st[mi] = __builtin_amdgcn_mfma_f32_16x16x32_bf16(kb, qa[mi][kc], st[mi], 0, 0, 0);
            }
#pragma unroll
            for (int mi = 0; mi < 4; ++mi) {
                uint32x2 u;
                u[0] = pack2(fmaxf(st[mi][0], 0.f), fmaxf(st[mi][1], 0.f));
                u[1] = pack2(fmaxf(st[mi][2], 0.f), fmaxf(st[mi][3], 0.f));
                *(uint32x2*)((char*)&lP[0][0] + (wv * 64 + mi * 16 + lo) * 72 + ni * 32 + hi * 8) = u;
            }
        }

        // ---- PV on lP + lV[buf] (wave-private lP rows, no barrier) ----
        {
            short8 vbf = *(const short8*)((const char*)lV[buf] + lo * 72 + hi * 16);
#pragma unroll
            for (int t = 0; t < 4; ++t) {
                short8 pa = *(const short8*)((const char*)&lP[0][0] + (wv * 64 + t * 16 + lo) * 72 + hi * 16);
                accout[t] = __builtin_amdgcn_mfma_f32_16x16x32_bf16(pa, vbf, accout[t], 0, 0, 0);
            }
        }

        // ---- late write of prefetched V (load issued early) ----
        if (pre) {
            unsigned int u = (chn < 15) ? pack2(vpre[0], vpre[1]) : 0x3F803F80u;
            *(unsigned int*)((char*)lV[buf ^ 1] + chn * 72 + kp * 4) = u;
        }
        __syncthreads();   // drains DMA (vmcnt) for buf^1 + lV writes; releases buf
        buf ^= 1;
    }

    // epilogue: divide by rowsum (ch 15) and store. D: lane lo = channel, (hi,r) = q.
#pragma unroll
    for (int t = 0; t < 4; ++t) {
#pragma unroll
        for (int r = 0; r < 4; ++r) {
            float rs = __shfl(accout[t][r], (lane & 48) | 15);
            if (lo < 15) {
                int q = qw0 + t * 16 + hi * 4 + r;
                out[(size_t)(b * 15 + lo) * 4096 + (size_t)(h0 + (q >> 5)) * 64 + (w0 + (q & 31))] =
                    accout[t][r] / (rs + 1e-6f);
            }
        }
    }
}

extern "C" void kernel_launch(void* const* d_in, const int* in_sizes, int n_in,
                              void* d_out, int out_size, void* d_ws, size_t ws_size,
                              hipStream_t stream) {
    const float* x = (const float*)d_in[0];
    const float* v = (const float*)d_in[1];
    const float* w = (const float*)d_in[2];
    float* out = (float*)d_out;

    unsigned short* qn  = (unsigned short*)d_ws;                         // 64 MiB (swizzled)
    unsigned short* wbf = (unsigned short*)((char*)d_ws + (size_t)128 * 1024 * 256 * 2);

    k0_cvt<<<512, 256, 0, stream>>>(w, wbf, 256 * 512);
    k1_qgemm<<<1024, 256, 0, stream>>>(x, wbf, qn);
    k2_attn<<<512, 256, 0, stream>>>(qn, v, out);
}